// Round 3
// baseline (156.056 us; speedup 1.0000x reference)
//
#include <hip/hip_runtime.h>
#include <stdint.h>

typedef __bf16 bf16;
typedef __bf16 bf16x8 __attribute__((ext_vector_type(8)));
typedef float f32x4 __attribute__((ext_vector_type(4)));

#define MFMA_16x16x32(a, b, c) __builtin_amdgcn_mfma_f32_16x16x32_bf16((a), (b), (c), 0, 0, 0)

// async global->LDS, 16B per lane. LDS dest is wave-uniform base + lane*16.
__device__ __forceinline__ void gl_lds16(const bf16* g, bf16* l) {
    __builtin_amdgcn_global_load_lds(
        (const __attribute__((address_space(1))) void*)g,
        (__attribute__((address_space(3))) void*)l, 16, 0, 0);
}

// f32 -> bf16 canonicalization of weight tensors
__global__ void cvt_kernel(const float* __restrict__ src, bf16* __restrict__ dst, int n) {
    int i = blockIdx.x * blockDim.x + threadIdx.x;
    if (i < n) dst[i] = (bf16)src[i];
}

// ---------------------------------------------------------------------------
// LayerNorm over E=512: one wave per row, 8 elems/lane. f32 in, bf16 out.
// ---------------------------------------------------------------------------
__global__ __launch_bounds__(256) void ln_kernel(const float* __restrict__ x,
                                                 const bf16* __restrict__ gamma,
                                                 const bf16* __restrict__ beta,
                                                 bf16* __restrict__ xn) {
    const int lane = threadIdx.x & 63;
    const int row = (blockIdx.x << 2) + (threadIdx.x >> 6);
    const size_t base = (size_t)row * 512 + lane * 8;
    const float* xf = x + base;
    float4 a = *(const float4*)xf;
    float4 b = *(const float4*)(xf + 4);
    float f[8] = {a.x, a.y, a.z, a.w, b.x, b.y, b.z, b.w};
    float s = 0.f;
#pragma unroll
    for (int j = 0; j < 8; ++j) s += f[j];
#pragma unroll
    for (int off = 32; off >= 1; off >>= 1) s += __shfl_xor(s, off, 64);
    const float mu = s * (1.0f / 512.0f);
    float vs = 0.f;
#pragma unroll
    for (int j = 0; j < 8; ++j) { float d = f[j] - mu; vs += d * d; }
#pragma unroll
    for (int off = 32; off >= 1; off >>= 1) vs += __shfl_xor(vs, off, 64);
    const float rstd = rsqrtf(vs * (1.0f / 512.0f) + 1e-5f);
    bf16x8 g = *(const bf16x8*)(gamma + lane * 8);
    bf16x8 bb = *(const bf16x8*)(beta + lane * 8);
    bf16x8 o;
#pragma unroll
    for (int j = 0; j < 8; ++j)
        o[j] = (bf16)((f[j] - mu) * rstd * (float)g[j] + (float)bb[j]);
    *(bf16x8*)(xn + base) = o;
}

// ---------------------------------------------------------------------------
// GEMM: C[M,N] = A[M,K] * B[N,K]^T + bias[N], bf16 in, fp32 accum, OT out.
// 128x128 tile, BK=32, m97 structure (global_load_lds + 2-barrier K loop).
// ---------------------------------------------------------------------------
template <typename OT>
__global__ __launch_bounds__(256) void gemm_bt(const bf16* __restrict__ A,
                                               const bf16* __restrict__ B,
                                               const bf16* __restrict__ bias,
                                               OT* __restrict__ C,
                                               int N, int K) {
    __shared__ alignas(16) bf16 As[128 * 32];
    __shared__ alignas(16) bf16 Bs[128 * 32];
    const int tid = threadIdx.x;
    const int lane = tid & 63;
    const int wid = tid >> 6;
    const int wm = (wid >> 1) * 64, wn = (wid & 1) * 64;
    const int m0 = blockIdx.y * 128, n0 = blockIdx.x * 128;
    const int l15 = lane & 15, l16 = lane >> 4;

    f32x4 acc[4][4] = {};

    const int c0 = tid, c1 = 256 + tid;
    const int ra0 = c0 >> 2, ka0 = (c0 & 3) * 8;
    const int ra1 = c1 >> 2, ka1 = (c1 & 3) * 8;
    const bf16* Abase = A + (size_t)m0 * K;
    const bf16* Bbase = B + (size_t)n0 * K;

    for (int k0 = 0; k0 < K; k0 += 32) {
        gl_lds16(Abase + (size_t)ra0 * K + k0 + ka0, &As[c0 * 8]);
        gl_lds16(Abase + (size_t)ra1 * K + k0 + ka1, &As[c1 * 8]);
        gl_lds16(Bbase + (size_t)ra0 * K + k0 + ka0, &Bs[c0 * 8]);
        gl_lds16(Bbase + (size_t)ra1 * K + k0 + ka1, &Bs[c1 * 8]);
        __syncthreads();
        bf16x8 af[4], bfr[4];
#pragma unroll
        for (int t = 0; t < 4; ++t) {
            af[t]  = *(const bf16x8*)&As[(wm + t * 16 + l15) * 32 + l16 * 8];
            bfr[t] = *(const bf16x8*)&Bs[(wn + t * 16 + l15) * 32 + l16 * 8];
        }
#pragma unroll
        for (int i = 0; i < 4; ++i)
#pragma unroll
            for (int j = 0; j < 4; ++j)
                acc[i][j] = MFMA_16x16x32(af[i], bfr[j], acc[i][j]);
        __syncthreads();
    }

    // C/D layout: col = lane&15, row = (lane>>4)*4 + reg
#pragma unroll
    for (int j = 0; j < 4; ++j) {
        const int col = n0 + wn + j * 16 + l15;
        const float bv = (float)bias[col];
#pragma unroll
        for (int i = 0; i < 4; ++i) {
            const int rbase = m0 + wm + i * 16 + l16 * 4;
#pragma unroll
            for (int r = 0; r < 4; ++r)
                C[(size_t)(rbase + r) * N + col] = (OT)(acc[i][j][r] + bv);
        }
    }
}

// ---------------------------------------------------------------------------
// Banded causal attention, flash-style. Block = 64 queries of one (b,h);
// 4 waves, each a 16-query tile with online softmax.
// Ks[key][d] stride 72, Vs[d][key] transposed stride 200 (16B-aligned rows).
// ---------------------------------------------------------------------------
#define KS_STRIDE 72
#define VS_STRIDE 200
#define PW_STRIDE 40

__global__ __launch_bounds__(256) void attn_kernel(const bf16* __restrict__ qkv,
                                                   bf16* __restrict__ ctx) {
    __shared__ alignas(16) bf16 Ks[192 * KS_STRIDE];
    __shared__ alignas(16) bf16 Vs[64 * VS_STRIDE];
    __shared__ alignas(16) bf16 Pbuf[4 * 16 * PW_STRIDE];

    const int tid = threadIdx.x;
    const int lane = tid & 63, wid = tid >> 6;
    const int l15 = lane & 15, l16 = lane >> 4;
    const int bh = blockIdx.y, b = bh >> 3, h = bh & 7;
    const int q0 = blockIdx.x * 64;
    const int kv0 = (q0 > 128) ? (q0 - 128) : 0;
    const int nk = q0 + 64 - kv0;
    const size_t tokbase = (size_t)b * 1024;

    for (int c = tid; c < nk * 8; c += 256) {
        const int kk = c >> 3, dc = (c & 7) * 8;
        const bf16* src = qkv + (tokbase + kv0 + kk) * 1536 + h * 64 + dc;
        uint4 kw = *(const uint4*)(src + 512);
        *(uint4*)&Ks[kk * KS_STRIDE + dc] = kw;
        uint4 vw = *(const uint4*)(src + 1024);
        const bf16* vp = (const bf16*)&vw;
#pragma unroll
        for (int j = 0; j < 8; ++j) Vs[(dc + j) * VS_STRIDE + kk] = vp[j];
    }

    const int qt0 = q0 + wid * 16;
    const bf16* qptr = qkv + (tokbase + qt0 + l15) * 1536 + h * 64;
    bf16x8 qa0 = *(const bf16x8*)(qptr + l16 * 8);
    bf16x8 qa1 = *(const bf16x8*)(qptr + 32 + l16 * 8);

    __syncthreads();

    bf16* Pw = &Pbuf[wid * 16 * PW_STRIDE];
    f32x4 of[4] = {};
    float mst[4], lst[4];
#pragma unroll
    for (int r = 0; r < 4; ++r) { mst[r] = -1e30f; lst[r] = 0.f; }

    const int ktstart = ((qt0 > 128) ? (qt0 - 128) : 0) & ~31;
    for (int kt = ktstart; kt <= qt0 + 15; kt += 32) {
        const int krel = kt - kv0;
        f32x4 s0 = {}, s1 = {};
        {
            const bf16* kb0 = &Ks[(krel + l15) * KS_STRIDE + l16 * 8];
            const bf16* kb1 = kb0 + 16 * KS_STRIDE;
            s0 = MFMA_16x16x32(qa0, *(const bf16x8*)kb0, s0);
            s0 = MFMA_16x16x32(qa1, *(const bf16x8*)(kb0 + 32), s0);
            s1 = MFMA_16x16x32(qa0, *(const bf16x8*)kb1, s1);
            s1 = MFMA_16x16x32(qa1, *(const bf16x8*)(kb1 + 32), s1);
        }
        float e0[4], e1[4];
#pragma unroll
        for (int r = 0; r < 4; ++r) {
            const int qa = qt0 + l16 * 4 + r;
            const int kg0 = kt + l15;
            const int kg1 = kg0 + 16;
            const bool ok0 = (kg0 <= qa) && (kg0 >= qa - 128);
            const bool ok1 = (kg1 <= qa) && (kg1 >= qa - 128);
            float v0 = ok0 ? s0[r] * 0.125f : -1e30f;
            float v1 = ok1 ? s1[r] * 0.125f : -1e30f;
            float mx = fmaxf(v0, v1);
#pragma unroll
            for (int off = 1; off < 16; off <<= 1)
                mx = fmaxf(mx, __shfl_xor(mx, off, 64));
            const float mnew = fmaxf(mst[r], mx);
            const float alpha = __expf(mst[r] - mnew);
            e0[r] = ok0 ? __expf(v0 - mnew) : 0.f;
            e1[r] = ok1 ? __expf(v1 - mnew) : 0.f;
            float rs = e0[r] + e1[r];
#pragma unroll
            for (int off = 1; off < 16; off <<= 1)
                rs += __shfl_xor(rs, off, 64);
            lst[r] = lst[r] * alpha + rs;
            mst[r] = mnew;
#pragma unroll
            for (int nt = 0; nt < 4; ++nt) of[nt][r] *= alpha;
        }
        // P: D-layout -> LDS -> A-operand layout
#pragma unroll
        for (int r = 0; r < 4; ++r) {
            const int q = l16 * 4 + r;
            Pw[q * PW_STRIDE + l15] = (bf16)e0[r];
            Pw[q * PW_STRIDE + 16 + l15] = (bf16)e1[r];
        }
        __asm__ volatile("s_waitcnt lgkmcnt(0)" ::: "memory");
        bf16x8 pa = *(const bf16x8*)&Pw[l15 * PW_STRIDE + l16 * 8];
#pragma unroll
        for (int nt = 0; nt < 4; ++nt) {
            const bf16* vb = &Vs[(nt * 16 + l15) * VS_STRIDE + krel + l16 * 8];
            of[nt] = MFMA_16x16x32(pa, *(const bf16x8*)vb, of[nt]);
        }
        __asm__ volatile("s_waitcnt lgkmcnt(0)" ::: "memory");
    }

    float linv[4];
#pragma unroll
    for (int r = 0; r < 4; ++r) linv[r] = 1.0f / lst[r];
    bf16* cbase = ctx + (tokbase + qt0) * 512 + h * 64;
#pragma unroll
    for (int nt = 0; nt < 4; ++nt)
#pragma unroll
        for (int r = 0; r < 4; ++r) {
            const int q = l16 * 4 + r;
            cbase[(size_t)q * 512 + nt * 16 + l15] = (bf16)(of[nt][r] * linv[r]);
        }
}

// ---------------------------------------------------------------------------
extern "C" void kernel_launch(void* const* d_in, const int* in_sizes, int n_in,
                              void* d_out, int out_size, void* d_ws, size_t ws_size,
                              hipStream_t stream) {
    const float* x     = (const float*)d_in[0];
    // d_in[1] = x_lengths (unused by reference)
    const float* gamma = (const float*)d_in[2];
    const float* beta  = (const float*)d_in[3];
    const float* w_in  = (const float*)d_in[4];
    const float* b_in  = (const float*)d_in[5];
    const float* w_out = (const float*)d_in[6];
    const float* b_out = (const float*)d_in[7];
    float* out = (float*)d_out;  // f32 output, written from fp32 accumulators

    char* ws = (char*)d_ws;
    bf16* cw_in  = (bf16*)ws;                              // 786432 elems
    bf16* cw_out = cw_in + 786432;                         // 262144
    bf16* cb_in  = cw_out + 262144;                        // 1536
    bf16* cb_out = cb_in + 1536;                           // 512
    bf16* cgam   = cb_out + 512;                           // 512
    bf16* cbet   = cgam + 512;                             // 512
    bf16* xn     = (bf16*)(ws + (4u << 20));               // 8 MB
    bf16* qkv    = (bf16*)(ws + (12u << 20));              // 24 MB
    bf16* ctx    = xn;                                     // reuse (xn dead after QKV GEMM)

    cvt_kernel<<<3072, 256, 0, stream>>>(w_in,  cw_in,  786432);
    cvt_kernel<<<1024, 256, 0, stream>>>(w_out, cw_out, 262144);
    cvt_kernel<<<6,    256, 0, stream>>>(b_in,  cb_in,  1536);
    cvt_kernel<<<2,    256, 0, stream>>>(b_out, cb_out, 512);
    cvt_kernel<<<2,    256, 0, stream>>>(gamma, cgam,   512);
    cvt_kernel<<<2,    256, 0, stream>>>(beta,  cbet,   512);

    ln_kernel<<<2048, 256, 0, stream>>>(x, cgam, cbet, xn);
    gemm_bt<bf16><<<dim3(12, 64), 256, 0, stream>>>(xn, cw_in, cb_in, qkv, 1536, 512);
    attn_kernel<<<dim3(16, 64), 256, 0, stream>>>(qkv, ctx);
    gemm_bt<float><<<dim3(4, 64), 256, 0, stream>>>(ctx, cw_out, cb_out, out, 512, 512);
}

// Round 4
// 142.385 us; speedup vs baseline: 1.0960x; 1.0960x over previous
//
#include <hip/hip_runtime.h>
#include <stdint.h>

typedef __bf16 bf16;
typedef __bf16 bf16x8 __attribute__((ext_vector_type(8)));
typedef float f32x4 __attribute__((ext_vector_type(4)));

#define MFMA_16x16x32(a, b, c) __builtin_amdgcn_mfma_f32_16x16x32_bf16((a), (b), (c), 0, 0, 0)

// async global->LDS, 16B per lane. LDS dest must be wave-uniform base + lane*16.
__device__ __forceinline__ void gl_lds16(const bf16* g, bf16* l) {
    __builtin_amdgcn_global_load_lds(
        (const __attribute__((address_space(1))) void*)g,
        (__attribute__((address_space(3))) void*)l, 16, 0, 0);
}

// ---------------------------------------------------------------------------
// prep: blocks [0,2048) = LayerNorm (4 rows each, f32 in, bf16 out, f32 g/b);
//       blocks [2048,2432) = w_in f32->bf16; [2432,2560) = w_out f32->bf16.
// ---------------------------------------------------------------------------
__global__ __launch_bounds__(256) void prep_kernel(const float* __restrict__ x,
                                                   const float* __restrict__ gamma,
                                                   const float* __restrict__ beta,
                                                   const float* __restrict__ w_in,
                                                   const float* __restrict__ w_out,
                                                   bf16* __restrict__ xn,
                                                   bf16* __restrict__ cw_in,
                                                   bf16* __restrict__ cw_out) {
    const int bid = blockIdx.x;
    if (bid < 2048) {
        const int lane = threadIdx.x & 63;
        const int row = (bid << 2) + (threadIdx.x >> 6);
        const size_t base = (size_t)row * 512 + lane * 8;
        const float* xf = x + base;
        float4 a = *(const float4*)xf;
        float4 b = *(const float4*)(xf + 4);
        float f[8] = {a.x, a.y, a.z, a.w, b.x, b.y, b.z, b.w};
        float s = 0.f;
#pragma unroll
        for (int j = 0; j < 8; ++j) s += f[j];
#pragma unroll
        for (int off = 32; off >= 1; off >>= 1) s += __shfl_xor(s, off, 64);
        const float mu = s * (1.0f / 512.0f);
        float vs = 0.f;
#pragma unroll
        for (int j = 0; j < 8; ++j) { float d = f[j] - mu; vs += d * d; }
#pragma unroll
        for (int off = 32; off >= 1; off >>= 1) vs += __shfl_xor(vs, off, 64);
        const float rstd = rsqrtf(vs * (1.0f / 512.0f) + 1e-5f);
        float4 g0 = *(const float4*)(gamma + lane * 8);
        float4 g1 = *(const float4*)(gamma + lane * 8 + 4);
        float4 b0 = *(const float4*)(beta + lane * 8);
        float4 b1 = *(const float4*)(beta + lane * 8 + 4);
        float gg[8] = {g0.x, g0.y, g0.z, g0.w, g1.x, g1.y, g1.z, g1.w};
        float bb[8] = {b0.x, b0.y, b0.z, b0.w, b1.x, b1.y, b1.z, b1.w};
        bf16x8 o;
#pragma unroll
        for (int j = 0; j < 8; ++j)
            o[j] = (bf16)((f[j] - mu) * rstd * gg[j] + bb[j]);
        *(bf16x8*)(xn + base) = o;
    } else {
        const float* src;
        bf16* dst;
        int base;
        if (bid < 2432) { src = w_in;  dst = cw_in;  base = (bid - 2048) * 2048; }
        else            { src = w_out; dst = cw_out; base = (bid - 2432) * 2048; }
        const int i = base + threadIdx.x * 8;
        float4 a = *(const float4*)(src + i);
        float4 b = *(const float4*)(src + i + 4);
        float f[8] = {a.x, a.y, a.z, a.w, b.x, b.y, b.z, b.w};
        bf16x8 o;
#pragma unroll
        for (int j = 0; j < 8; ++j) o[j] = (bf16)f[j];
        *(bf16x8*)(dst + i) = o;
    }
}

// ---------------------------------------------------------------------------
// GEMM: C[M,N] = A[M,K] * B[N,K]^T + bias[N]. bf16 in, fp32 accum, OT out.
// Tile TM x 128, BK=32, m97 structure. TM=128: waves 2x2 of 64x64 (4x4 frags).
// TM=64: waves 2x2 of 32x64 (2x4 frags) -> 2x the blocks for occupancy.
// ---------------------------------------------------------------------------
template <int TM, typename OT>
__global__ __launch_bounds__(256) void gemm_bt(const bf16* __restrict__ A,
                                               const bf16* __restrict__ B,
                                               const float* __restrict__ bias,
                                               OT* __restrict__ C,
                                               int N, int K) {
    constexpr int MI = TM / 32;  // m-frags per wave
    __shared__ alignas(16) bf16 As[TM * 32];
    __shared__ alignas(16) bf16 Bs[128 * 32];
    const int tid = threadIdx.x;
    const int lane = tid & 63;
    const int wid = tid >> 6;
    const int wm = (wid >> 1) * (TM / 2), wn = (wid & 1) * 64;
    const int m0 = blockIdx.y * TM, n0 = blockIdx.x * 128;
    const int l15 = lane & 15, l16 = lane >> 4;

    f32x4 acc[MI][4] = {};

    const bf16* Abase = A + (size_t)m0 * K;
    const bf16* Bbase = B + (size_t)n0 * K;

    for (int k0 = 0; k0 < K; k0 += 32) {
#pragma unroll
        for (int c = tid; c < TM * 4; c += 256)
            gl_lds16(Abase + (size_t)(c >> 2) * K + k0 + (c & 3) * 8, &As[c * 8]);
#pragma unroll
        for (int c = tid; c < 512; c += 256)
            gl_lds16(Bbase + (size_t)(c >> 2) * K + k0 + (c & 3) * 8, &Bs[c * 8]);
        __syncthreads();
        bf16x8 af[MI], bfr[4];
#pragma unroll
        for (int t = 0; t < MI; ++t)
            af[t] = *(const bf16x8*)&As[(wm + t * 16 + l15) * 32 + l16 * 8];
#pragma unroll
        for (int t = 0; t < 4; ++t)
            bfr[t] = *(const bf16x8*)&Bs[(wn + t * 16 + l15) * 32 + l16 * 8];
#pragma unroll
        for (int i = 0; i < MI; ++i)
#pragma unroll
            for (int j = 0; j < 4; ++j)
                acc[i][j] = MFMA_16x16x32(af[i], bfr[j], acc[i][j]);
        __syncthreads();
    }

    // C/D layout: col = lane&15, row = (lane>>4)*4 + reg
#pragma unroll
    for (int j = 0; j < 4; ++j) {
        const int col = n0 + wn + j * 16 + l15;
        const float bv = bias[col];
#pragma unroll
        for (int i = 0; i < MI; ++i) {
            const int rbase = m0 + wm + i * 16 + l16 * 4;
#pragma unroll
            for (int r = 0; r < 4; ++r)
                C[(size_t)(rbase + r) * N + col] = (OT)(acc[i][j][r] + bv);
        }
    }
}

// ---------------------------------------------------------------------------
// Banded causal attention, flash-style. Block = 64 queries of one (b,h);
// 4 waves, each a 16-query tile with online softmax.
// Ks[key][d] stride 72 (b128-friendly). V stored NATURAL Vn[key][d] stride 74:
// staging via 4x b32 writes (37-dword lane delta, odd -> conflict-free);
// PV B-frags read scalar (l16-groups at +8 banks, l15 pairs same-dword
// broadcast -> conflict-free). Row clamp kills OOB-garbage x0 NaN hazard.
// ---------------------------------------------------------------------------
#define KS_STRIDE 72
#define VN_STRIDE 74
#define PW_STRIDE 40

__global__ __launch_bounds__(256) void attn_kernel(const bf16* __restrict__ qkv,
                                                   bf16* __restrict__ ctx) {
    __shared__ alignas(16) bf16 Ks[192 * KS_STRIDE];
    __shared__ alignas(16) bf16 Vn[192 * VN_STRIDE];
    __shared__ alignas(16) bf16 Pbuf[4 * 16 * PW_STRIDE];

    const int tid = threadIdx.x;
    const int lane = tid & 63, wid = tid >> 6;
    const int l15 = lane & 15, l16 = lane >> 4;
    const int bh = blockIdx.y, b = bh >> 3, h = bh & 7;
    const int q0 = blockIdx.x * 64;
    const int kv0 = (q0 > 128) ? (q0 - 128) : 0;
    const int nk = q0 + 64 - kv0;  // 64 / 128 / 192
    const size_t tokbase = (size_t)b * 1024;

    for (int c = tid; c < nk * 8; c += 256) {
        const int kk = c >> 3, dc = (c & 7) * 8;
        const bf16* src = qkv + (tokbase + kv0 + kk) * 1536 + h * 64 + dc;
        uint4 kw = *(const uint4*)(src + 512);
        *(uint4*)&Ks[kk * KS_STRIDE + dc] = kw;
        uint4 vw = *(const uint4*)(src + 1024);
        uint* vdst = (uint*)&Vn[kk * VN_STRIDE + dc];
        vdst[0] = vw.x; vdst[1] = vw.y; vdst[2] = vw.z; vdst[3] = vw.w;
    }

    const int qt0 = q0 + wid * 16;
    const bf16* qptr = qkv + (tokbase + qt0 + l15) * 1536 + h * 64;
    bf16x8 qa0 = *(const bf16x8*)(qptr + l16 * 8);
    bf16x8 qa1 = *(const bf16x8*)(qptr + 32 + l16 * 8);

    __syncthreads();

    bf16* Pw = &Pbuf[wid * 16 * PW_STRIDE];
    f32x4 of[4] = {};
    float mst[4], lst[4];
#pragma unroll
    for (int r = 0; r < 4; ++r) { mst[r] = -1e30f; lst[r] = 0.f; }

    const int ktstart = ((qt0 > 128) ? (qt0 - 128) : 0) & ~31;
    for (int kt = ktstart; kt <= qt0 + 15; kt += 32) {
        const int krel = kt - kv0;
        f32x4 s0 = {}, s1 = {};
        {
            const bf16* kb0 = &Ks[(krel + l15) * KS_STRIDE + l16 * 8];
            const bf16* kb1 = kb0 + 16 * KS_STRIDE;
            s0 = MFMA_16x16x32(qa0, *(const bf16x8*)kb0, s0);
            s0 = MFMA_16x16x32(qa1, *(const bf16x8*)(kb0 + 32), s0);
            s1 = MFMA_16x16x32(qa0, *(const bf16x8*)kb1, s1);
            s1 = MFMA_16x16x32(qa1, *(const bf16x8*)(kb1 + 32), s1);
        }
        float e0[4], e1[4];
#pragma unroll
        for (int r = 0; r < 4; ++r) {
            const int qa = qt0 + l16 * 4 + r;
            const int kg0 = kt + l15;
            const int kg1 = kg0 + 16;
            const bool ok0 = (kg0 <= qa) && (kg0 >= qa - 128);
            const bool ok1 = (kg1 <= qa) && (kg1 >= qa - 128);
            float v0 = ok0 ? s0[r] * 0.125f : -1e30f;
            float v1 = ok1 ? s1[r] * 0.125f : -1e30f;
            float mx = fmaxf(v0, v1);
#pragma unroll
            for (int off = 1; off < 16; off <<= 1)
                mx = fmaxf(mx, __shfl_xor(mx, off, 64));
            const float mnew = fmaxf(mst[r], mx);
            const float alpha = __expf(mst[r] - mnew);
            e0[r] = ok0 ? __expf(v0 - mnew) : 0.f;
            e1[r] = ok1 ? __expf(v1 - mnew) : 0.f;
            float rs = e0[r] + e1[r];
#pragma unroll
            for (int off = 1; off < 16; off <<= 1)
                rs += __shfl_xor(rs, off, 64);
            lst[r] = lst[r] * alpha + rs;
            mst[r] = mnew;
#pragma unroll
            for (int nt = 0; nt < 4; ++nt) of[nt][r] *= alpha;
        }
        // P: D-layout -> LDS -> A-operand layout
#pragma unroll
        for (int r = 0; r < 4; ++r) {
            const int q = l16 * 4 + r;
            Pw[q * PW_STRIDE + l15] = (bf16)e0[r];
            Pw[q * PW_STRIDE + 16 + l15] = (bf16)e1[r];
        }
        __asm__ volatile("s_waitcnt lgkmcnt(0)" ::: "memory");
        bf16x8 pa = *(const bf16x8*)&Pw[l15 * PW_STRIDE + l16 * 8];
        // O += P V : B-frag scalar from natural Vn, rows clamped to staged range
        int row[8];
#pragma unroll
        for (int j = 0; j < 8; ++j) {
            int rr = krel + l16 * 8 + j;
            row[j] = (rr < nk) ? rr : (nk - 1);
        }
#pragma unroll
        for (int nt = 0; nt < 4; ++nt) {
            bf16x8 vb;
#pragma unroll
            for (int j = 0; j < 8; ++j)
                vb[j] = Vn[row[j] * VN_STRIDE + nt * 16 + l15];
            of[nt] = MFMA_16x16x32(pa, vb, of[nt]);
        }
        __asm__ volatile("s_waitcnt lgkmcnt(0)" ::: "memory");
    }

    float linv[4];
#pragma unroll
    for (int r = 0; r < 4; ++r) linv[r] = 1.0f / lst[r];
    bf16* cbase = ctx + (tokbase + qt0) * 512 + h * 64;
#pragma unroll
    for (int nt = 0; nt < 4; ++nt)
#pragma unroll
        for (int r = 0; r < 4; ++r) {
            const int q = l16 * 4 + r;
            cbase[(size_t)q * 512 + nt * 16 + l15] = (bf16)(of[nt][r] * linv[r]);
        }
}

// ---------------------------------------------------------------------------
extern "C" void kernel_launch(void* const* d_in, const int* in_sizes, int n_in,
                              void* d_out, int out_size, void* d_ws, size_t ws_size,
                              hipStream_t stream) {
    const float* x     = (const float*)d_in[0];
    // d_in[1] = x_lengths (unused by reference)
    const float* gamma = (const float*)d_in[2];
    const float* beta  = (const float*)d_in[3];
    const float* w_in  = (const float*)d_in[4];
    const float* b_in  = (const float*)d_in[5];
    const float* w_out = (const float*)d_in[6];
    const float* b_out = (const float*)d_in[7];
    float* out = (float*)d_out;

    char* ws = (char*)d_ws;
    bf16* cw_in  = (bf16*)ws;                   // 786432 elems (1.5 MB)
    bf16* cw_out = cw_in + 786432;              // 262144 (0.5 MB)
    bf16* xn     = (bf16*)(ws + (4u << 20));    // 8 MB
    bf16* qkv    = (bf16*)(ws + (12u << 20));   // 24 MB
    bf16* ctx    = xn;                          // xn dead after QKV GEMM

    prep_kernel<<<2560, 256, 0, stream>>>(x, gamma, beta, w_in, w_out, xn, cw_in, cw_out);
    gemm_bt<128, bf16><<<dim3(12, 64), 256, 0, stream>>>(xn, cw_in, b_in, qkv, 1536, 512);
    attn_kernel<<<dim3(16, 64), 256, 0, stream>>>(qkv, ctx);
    gemm_bt<64, float><<<dim3(4, 128), 256, 0, stream>>>(ctx, cw_out, b_out, out, 512, 512);
}

// Round 5
// 138.323 us; speedup vs baseline: 1.1282x; 1.0294x over previous
//
#include <hip/hip_runtime.h>
#include <stdint.h>

typedef __bf16 bf16;
typedef __bf16 bf16x8 __attribute__((ext_vector_type(8)));
typedef float f32x4 __attribute__((ext_vector_type(4)));

#define MFMA_16x16x32(a, b, c) __builtin_amdgcn_mfma_f32_16x16x32_bf16((a), (b), (c), 0, 0, 0)

// async global->LDS, 16B per lane. LDS dest must be wave-uniform base + lane*16.
__device__ __forceinline__ void gl_lds16(const bf16* g, bf16* l) {
    __builtin_amdgcn_global_load_lds(
        (const __attribute__((address_space(1))) void*)g,
        (__attribute__((address_space(3))) void*)l, 16, 0, 0);
}

// ---------------------------------------------------------------------------
// prep: blocks [0,2048) = LayerNorm (4 rows each, f32 in, bf16 out, f32 g/b);
//       blocks [2048,2432) = w_in f32->bf16; [2432,2560) = w_out f32->bf16.
// ---------------------------------------------------------------------------
__global__ __launch_bounds__(256) void prep_kernel(const float* __restrict__ x,
                                                   const float* __restrict__ gamma,
                                                   const float* __restrict__ beta,
                                                   const float* __restrict__ w_in,
                                                   const float* __restrict__ w_out,
                                                   bf16* __restrict__ xn,
                                                   bf16* __restrict__ cw_in,
                                                   bf16* __restrict__ cw_out) {
    const int bid = blockIdx.x;
    if (bid < 2048) {
        const int lane = threadIdx.x & 63;
        const int row = (bid << 2) + (threadIdx.x >> 6);
        const size_t base = (size_t)row * 512 + lane * 8;
        const float* xf = x + base;
        float4 a = *(const float4*)xf;
        float4 b = *(const float4*)(xf + 4);
        float f[8] = {a.x, a.y, a.z, a.w, b.x, b.y, b.z, b.w};
        float s = 0.f;
#pragma unroll
        for (int j = 0; j < 8; ++j) s += f[j];
#pragma unroll
        for (int off = 32; off >= 1; off >>= 1) s += __shfl_xor(s, off, 64);
        const float mu = s * (1.0f / 512.0f);
        float vs = 0.f;
#pragma unroll
        for (int j = 0; j < 8; ++j) { float d = f[j] - mu; vs += d * d; }
#pragma unroll
        for (int off = 32; off >= 1; off >>= 1) vs += __shfl_xor(vs, off, 64);
        const float rstd = rsqrtf(vs * (1.0f / 512.0f) + 1e-5f);
        float4 g0 = *(const float4*)(gamma + lane * 8);
        float4 g1 = *(const float4*)(gamma + lane * 8 + 4);
        float4 b0 = *(const float4*)(beta + lane * 8);
        float4 b1 = *(const float4*)(beta + lane * 8 + 4);
        float gg[8] = {g0.x, g0.y, g0.z, g0.w, g1.x, g1.y, g1.z, g1.w};
        float bb[8] = {b0.x, b0.y, b0.z, b0.w, b1.x, b1.y, b1.z, b1.w};
        bf16x8 o;
#pragma unroll
        for (int j = 0; j < 8; ++j)
            o[j] = (bf16)((f[j] - mu) * rstd * gg[j] + bb[j]);
        *(bf16x8*)(xn + base) = o;
    } else {
        const float* src;
        bf16* dst;
        int base;
        if (bid < 2432) { src = w_in;  dst = cw_in;  base = (bid - 2048) * 2048; }
        else            { src = w_out; dst = cw_out; base = (bid - 2432) * 2048; }
        const int i = base + threadIdx.x * 8;
        float4 a = *(const float4*)(src + i);
        float4 b = *(const float4*)(src + i + 4);
        float f[8] = {a.x, a.y, a.z, a.w, b.x, b.y, b.z, b.w};
        bf16x8 o;
#pragma unroll
        for (int j = 0; j < 8; ++j) o[j] = (bf16)f[j];
        *(bf16x8*)(dst + i) = o;
    }
}

// ---------------------------------------------------------------------------
// GEMM: C[M,N] = A[M,K] * B[N,K]^T + bias[N]. bf16 in, fp32 accum, OT out.
// Tile TM x 128, BK=64 as TWO stride-32 panels concatenated in LDS:
// chunk c -> panel p=c/(TM*4), row r=(c%(TM*4))>>2, koff (c&3)*8+p*32,
// LDS addr = c*8 (contiguous lane order, valid for global_load_lds), and
// frag reads keep the phase-optimal 16-dword row stride. 8 K-iters (vs 16)
// -> half the barrier/vmcnt(0) drains of the BK=32 m97 structure.
// ---------------------------------------------------------------------------
template <int TM, typename OT>
__global__ __launch_bounds__(256) void gemm_bt(const bf16* __restrict__ A,
                                               const bf16* __restrict__ B,
                                               const float* __restrict__ bias,
                                               OT* __restrict__ C,
                                               int N, int K) {
    constexpr int MI = TM / 32;          // m-frags per wave
    constexpr int NCA = TM * 8;          // A 16B-chunks per K-tile
    __shared__ alignas(16) bf16 As[TM * 64];
    __shared__ alignas(16) bf16 Bs[128 * 64];
    const int tid = threadIdx.x;
    const int lane = tid & 63;
    const int wid = tid >> 6;
    const int wm = (wid >> 1) * (TM / 2), wn = (wid & 1) * 64;
    const int m0 = blockIdx.y * TM, n0 = blockIdx.x * 128;
    const int l15 = lane & 15, l16 = lane >> 4;

    f32x4 acc[MI][4] = {};

    const bf16* Abase = A + (size_t)m0 * K;
    const bf16* Bbase = B + (size_t)n0 * K;

    for (int k0 = 0; k0 < K; k0 += 64) {
#pragma unroll
        for (int c = tid; c < NCA; c += 256) {
            const int p = c / (TM * 4);
            const int r = (c % (TM * 4)) >> 2;
            const int ko = (c & 3) * 8 + p * 32;
            gl_lds16(Abase + (size_t)r * K + k0 + ko, &As[c * 8]);
        }
#pragma unroll
        for (int c = tid; c < 1024; c += 256) {
            const int p = c >> 9;
            const int r = (c & 511) >> 2;
            const int ko = (c & 3) * 8 + p * 32;
            gl_lds16(Bbase + (size_t)r * K + k0 + ko, &Bs[c * 8]);
        }
        __syncthreads();
#pragma unroll
        for (int h = 0; h < 2; ++h) {
            bf16x8 af[MI], bfr[4];
#pragma unroll
            for (int t = 0; t < MI; ++t)
                af[t] = *(const bf16x8*)&As[h * (TM * 32) + (wm + t * 16 + l15) * 32 + l16 * 8];
#pragma unroll
            for (int t = 0; t < 4; ++t)
                bfr[t] = *(const bf16x8*)&Bs[h * 4096 + (wn + t * 16 + l15) * 32 + l16 * 8];
#pragma unroll
            for (int i = 0; i < MI; ++i)
#pragma unroll
                for (int j = 0; j < 4; ++j)
                    acc[i][j] = MFMA_16x16x32(af[i], bfr[j], acc[i][j]);
        }
        __syncthreads();
    }

    // C/D layout: col = lane&15, row = (lane>>4)*4 + reg
#pragma unroll
    for (int j = 0; j < 4; ++j) {
        const int col = n0 + wn + j * 16 + l15;
        const float bv = bias[col];
#pragma unroll
        for (int i = 0; i < MI; ++i) {
            const int rbase = m0 + wm + i * 16 + l16 * 4;
#pragma unroll
            for (int r = 0; r < 4; ++r)
                C[(size_t)(rbase + r) * N + col] = (OT)(acc[i][j][r] + bv);
        }
    }
}

// ---------------------------------------------------------------------------
// Banded causal attention, flash-style. Block = 64 queries of one (b,h);
// 4 waves, each a 16-query tile with online softmax.
// Ks[key][d] stride 72 (b128-friendly). V stored NATURAL Vn[key][d] stride 74:
// staging via 4x b32 writes (conflict-free); PV B-frags read scalar
// (l16-groups at +8 banks, l15 pairs same-dword broadcast -> conflict-free).
// Row clamp kills OOB-garbage x0 NaN hazard.
// ---------------------------------------------------------------------------
#define KS_STRIDE 72
#define VN_STRIDE 74
#define PW_STRIDE 40

__global__ __launch_bounds__(256) void attn_kernel(const bf16* __restrict__ qkv,
                                                   bf16* __restrict__ ctx) {
    __shared__ alignas(16) bf16 Ks[192 * KS_STRIDE];
    __shared__ alignas(16) bf16 Vn[192 * VN_STRIDE];
    __shared__ alignas(16) bf16 Pbuf[4 * 16 * PW_STRIDE];

    const int tid = threadIdx.x;
    const int lane = tid & 63, wid = tid >> 6;
    const int l15 = lane & 15, l16 = lane >> 4;
    const int bh = blockIdx.y, b = bh >> 3, h = bh & 7;
    const int q0 = blockIdx.x * 64;
    const int kv0 = (q0 > 128) ? (q0 - 128) : 0;
    const int nk = q0 + 64 - kv0;  // 64 / 128 / 192
    const size_t tokbase = (size_t)b * 1024;

    for (int c = tid; c < nk * 8; c += 256) {
        const int kk = c >> 3, dc = (c & 7) * 8;
        const bf16* src = qkv + (tokbase + kv0 + kk) * 1536 + h * 64 + dc;
        uint4 kw = *(const uint4*)(src + 512);
        *(uint4*)&Ks[kk * KS_STRIDE + dc] = kw;
        uint4 vw = *(const uint4*)(src + 1024);
        uint* vdst = (uint*)&Vn[kk * VN_STRIDE + dc];
        vdst[0] = vw.x; vdst[1] = vw.y; vdst[2] = vw.z; vdst[3] = vw.w;
    }

    const int qt0 = q0 + wid * 16;
    const bf16* qptr = qkv + (tokbase + qt0 + l15) * 1536 + h * 64;
    bf16x8 qa0 = *(const bf16x8*)(qptr + l16 * 8);
    bf16x8 qa1 = *(const bf16x8*)(qptr + 32 + l16 * 8);

    __syncthreads();

    bf16* Pw = &Pbuf[wid * 16 * PW_STRIDE];
    f32x4 of[4] = {};
    float mst[4], lst[4];
#pragma unroll
    for (int r = 0; r < 4; ++r) { mst[r] = -1e30f; lst[r] = 0.f; }

    const int ktstart = ((qt0 > 128) ? (qt0 - 128) : 0) & ~31;
    for (int kt = ktstart; kt <= qt0 + 15; kt += 32) {
        const int krel = kt - kv0;
        f32x4 s0 = {}, s1 = {};
        {
            const bf16* kb0 = &Ks[(krel + l15) * KS_STRIDE + l16 * 8];
            const bf16* kb1 = kb0 + 16 * KS_STRIDE;
            s0 = MFMA_16x16x32(qa0, *(const bf16x8*)kb0, s0);
            s0 = MFMA_16x16x32(qa1, *(const bf16x8*)(kb0 + 32), s0);
            s1 = MFMA_16x16x32(qa0, *(const bf16x8*)kb1, s1);
            s1 = MFMA_16x16x32(qa1, *(const bf16x8*)(kb1 + 32), s1);
        }
        float e0[4], e1[4];
#pragma unroll
        for (int r = 0; r < 4; ++r) {
            const int qa = qt0 + l16 * 4 + r;
            const int kg0 = kt + l15;
            const int kg1 = kg0 + 16;
            const bool ok0 = (kg0 <= qa) && (kg0 >= qa - 128);
            const bool ok1 = (kg1 <= qa) && (kg1 >= qa - 128);
            float v0 = ok0 ? s0[r] * 0.125f : -1e30f;
            float v1 = ok1 ? s1[r] * 0.125f : -1e30f;
            float mx = fmaxf(v0, v1);
#pragma unroll
            for (int off = 1; off < 16; off <<= 1)
                mx = fmaxf(mx, __shfl_xor(mx, off, 64));
            const float mnew = fmaxf(mst[r], mx);
            const float alpha = __expf(mst[r] - mnew);
            e0[r] = ok0 ? __expf(v0 - mnew) : 0.f;
            e1[r] = ok1 ? __expf(v1 - mnew) : 0.f;
            float rs = e0[r] + e1[r];
#pragma unroll
            for (int off = 1; off < 16; off <<= 1)
                rs += __shfl_xor(rs, off, 64);
            lst[r] = lst[r] * alpha + rs;
            mst[r] = mnew;
#pragma unroll
            for (int nt = 0; nt < 4; ++nt) of[nt][r] *= alpha;
        }
        // P: D-layout -> LDS -> A-operand layout
#pragma unroll
        for (int r = 0; r < 4; ++r) {
            const int q = l16 * 4 + r;
            Pw[q * PW_STRIDE + l15] = (bf16)e0[r];
            Pw[q * PW_STRIDE + 16 + l15] = (bf16)e1[r];
        }
        __asm__ volatile("s_waitcnt lgkmcnt(0)" ::: "memory");
        bf16x8 pa = *(const bf16x8*)&Pw[l15 * PW_STRIDE + l16 * 8];
        // O += P V : B-frag scalar from natural Vn, rows clamped to staged range
        int row[8];
#pragma unroll
        for (int j = 0; j < 8; ++j) {
            int rr = krel + l16 * 8 + j;
            row[j] = (rr < nk) ? rr : (nk - 1);
        }
#pragma unroll
        for (int nt = 0; nt < 4; ++nt) {
            bf16x8 vb;
#pragma unroll
            for (int j = 0; j < 8; ++j)
                vb[j] = Vn[row[j] * VN_STRIDE + nt * 16 + l15];
            of[nt] = MFMA_16x16x32(pa, vb, of[nt]);
        }
        __asm__ volatile("s_waitcnt lgkmcnt(0)" ::: "memory");
    }

    float linv[4];
#pragma unroll
    for (int r = 0; r < 4; ++r) linv[r] = 1.0f / lst[r];
    bf16* cbase = ctx + (tokbase + qt0) * 512 + h * 64;
#pragma unroll
    for (int nt = 0; nt < 4; ++nt)
#pragma unroll
        for (int r = 0; r < 4; ++r) {
            const int q = l16 * 4 + r;
            cbase[(size_t)q * 512 + nt * 16 + l15] = (bf16)(of[nt][r] * linv[r]);
        }
}

// ---------------------------------------------------------------------------
extern "C" void kernel_launch(void* const* d_in, const int* in_sizes, int n_in,
                              void* d_out, int out_size, void* d_ws, size_t ws_size,
                              hipStream_t stream) {
    const float* x     = (const float*)d_in[0];
    // d_in[1] = x_lengths (unused by reference)
    const float* gamma = (const float*)d_in[2];
    const float* beta  = (const float*)d_in[3];
    const float* w_in  = (const float*)d_in[4];
    const float* b_in  = (const float*)d_in[5];
    const float* w_out = (const float*)d_in[6];
    const float* b_out = (const float*)d_in[7];
    float* out = (float*)d_out;

    char* ws = (char*)d_ws;
    bf16* cw_in  = (bf16*)ws;                   // 786432 elems (1.5 MB)
    bf16* cw_out = cw_in + 786432;              // 262144 (0.5 MB)
    bf16* xn     = (bf16*)(ws + (4u << 20));    // 8 MB
    bf16* qkv    = (bf16*)(ws + (12u << 20));   // 24 MB
    bf16* ctx    = xn;                          // xn dead after QKV GEMM

    prep_kernel<<<2560, 256, 0, stream>>>(x, gamma, beta, w_in, w_out, xn, cw_in, cw_out);
    gemm_bt<128, bf16><<<dim3(12, 64), 256, 0, stream>>>(xn, cw_in, b_in, qkv, 1536, 512);
    attn_kernel<<<dim3(16, 64), 256, 0, stream>>>(qkv, ctx);
    gemm_bt<64, float><<<dim3(4, 128), 256, 0, stream>>>(ctx, cw_out, b_out, out, 512, 512);
}